// Round 9
// baseline (88.240 us; speedup 1.0000x reference)
//
#include <hip/hip_runtime.h>
#include <math.h>

#define B   1024
#define IN  1024
#define HID 1024
#define OUT 512
#define T   100

// k_main grid: [0, NDRV) drive | [NDRV, +NW1D) w1d partials | [.., +NRSUM) fc2 rowsums
// drive: 4 waves/block, 4 consecutive rows per wave -> 16 rows (64KB) per block,
// in dispatch order => dense sequential HBM sweep.
#define RPW    4
#define NDRV   (B * T / (4 * RPW))   // 6400
#define NW1D   64
#define NRSUM  128

typedef float v4f __attribute__((ext_vector_type(4)));

// ---------------------------------------------------------------------------
// ws layout (floats):
//   [0, 16384)            w1d partials (16 h-chunks x 1024 b)
//   [16384, 16896)        rowsum_fc2[o]
//   [16896, 16896+T*B)    drive[t*B+b]
// ---------------------------------------------------------------------------

__device__ __forceinline__ float delay_of(const float* lor, float cdv) {
    float v = fminf(fmaxf(lor[0], 0.0f), 0.999f);
    float g = 1.0f / sqrtf(1.0f - v * v);
    return expf(-g * fabsf(cdv) * v);
}

__global__ __launch_bounds__(256) void k_main(const float* __restrict__ x,
                                              const float* __restrict__ cd,
                                              const float* __restrict__ fc1_w,
                                              const float* __restrict__ fc2_w,
                                              const float* __restrict__ lor,
                                              float* __restrict__ drive,
                                              float* __restrict__ partial,
                                              float* __restrict__ rowsum) {
    int blk = blockIdx.x;
    int tid = threadIdx.x;
    if (blk < NDRV) {
        // ---- drive: 4 consecutive rows per wave ----
        __shared__ float dly[IN];
        #pragma unroll
        for (int k = 0; k < 4; ++k) {
            int i = k * 256 + tid;
            dly[i] = delay_of(lor, cd[i]);
        }
        __syncthreads();
        int lane = tid & 63;
        const v4f* dl = (const v4f*)dly;
        v4f dv0 = dl[0 * 64 + lane];
        v4f dv1 = dl[1 * 64 + lane];
        v4f dv2 = dl[2 * 64 + lane];
        v4f dv3 = dl[3 * 64 + lane];
        int r0 = (blk * 4 + (tid >> 6)) * RPW;       // first of RPW consecutive rows
        float accs[RPW];
        #pragma unroll
        for (int j = 0; j < RPW; ++j) {
            const v4f* xr = (const v4f*)(x + (size_t)(r0 + j) * IN);
            v4f x0 = __builtin_nontemporal_load(xr + 0 * 64 + lane);
            v4f x1 = __builtin_nontemporal_load(xr + 1 * 64 + lane);
            v4f x2 = __builtin_nontemporal_load(xr + 2 * 64 + lane);
            v4f x3 = __builtin_nontemporal_load(xr + 3 * 64 + lane);
            accs[j] = x0.x * dv0.x + x0.y * dv0.y + x0.z * dv0.z + x0.w * dv0.w
                    + x1.x * dv1.x + x1.y * dv1.y + x1.z * dv1.z + x1.w * dv1.w
                    + x2.x * dv2.x + x2.y * dv2.y + x2.z * dv2.z + x2.w * dv2.w
                    + x3.x * dv3.x + x3.y * dv3.y + x3.z * dv3.z + x3.w * dv3.w;
        }
        #pragma unroll
        for (int j = 0; j < RPW; ++j) {
            float acc = accs[j];
            #pragma unroll
            for (int off = 32; off; off >>= 1) acc += __shfl_xor(acc, off);
            if (lane == 0) {
                int r = r0 + j;
                int b = r / T;
                int t = r - b * T;
                drive[t * B + b] = acc;
            }
        }
    } else if (blk < NDRV + NW1D) {
        // ---- w1d partials: hc = q>>2 (h-chunk of 64), bb = q&3 ----
        __shared__ float dly[64];
        int q = blk - NDRV;
        int hc = q >> 2, bb = q & 3;
        int h0 = hc * 64;
        if (tid < 64) dly[tid] = delay_of(lor, cd[h0 + tid]);
        __syncthreads();
        int b = bb * 256 + tid;
        float acc = 0.0f;
        #pragma unroll 8
        for (int k = 0; k < 64; ++k)
            acc += fc1_w[(size_t)(h0 + k) * IN + b] * dly[k];
        partial[hc * IN + b] = acc;
    } else {
        // ---- fc2 rowsums: one wave per output row ----
        int gw = ((blk - NDRV - NW1D) * 256 + tid) >> 6;     // 512 waves -> OUT rows
        int lane = tid & 63;
        const float4* r = (const float4*)(fc2_w + (size_t)gw * HID);
        float acc = 0.0f;
        #pragma unroll
        for (int k = 0; k < 4; ++k) {
            float4 v = r[k * 64 + lane];
            acc += v.x + v.y + v.z + v.w;
        }
        #pragma unroll
        for (int off = 32; off; off >>= 1) acc += __shfl_xor(acc, off);
        if (lane == 0) rowsum[gw] = acc;
    }
}

// single block, 1024 threads: c1 + w1d combine + chunked LIF scan + hm scan + output
__global__ __launch_bounds__(1024) void k_scan(const float* __restrict__ drive,
                                               const float* __restrict__ partial,
                                               const float* __restrict__ cd,
                                               const float* __restrict__ fc1_b,
                                               const float* __restrict__ fc2_b,
                                               const float* __restrict__ ta,
                                               const float* __restrict__ lor,
                                               const float* __restrict__ ibeta,
                                               const float* __restrict__ hbeta,
                                               const float* __restrict__ ithr,
                                               const float* __restrict__ hthr,
                                               const float* __restrict__ rowsum,
                                               float* __restrict__ out) {
    __shared__ float cbuf[16][B];   // 64 KB
    __shared__ float red[16];
    __shared__ float S[T];
    __shared__ float ta_l[T];
    __shared__ float sc[4];         // [0]=c1, [1]=wsum, [2]=tasum
    int b = threadIdx.x, wave = b >> 6, lane = b & 63;

    if (b < T) ta_l[b] = ta[b];

    float d = delay_of(lor, cd[b]);
    float c = fc1_b[b] * d;
    #pragma unroll
    for (int off = 32; off; off >>= 1) c += __shfl_xor(c, off);
    if (lane == 0) red[wave] = c;
    __syncthreads();
    if (b == 0) {
        float s = 0.0f;
        #pragma unroll
        for (int k = 0; k < 16; ++k) s += red[k];
        sc[0] = s;
    }

    float w = 0.0f;
    #pragma unroll
    for (int cc = 0; cc < 16; ++cc) w += partial[cc * IN + b];

    float ib = ibeta[0], it = ithr[0];
    float im = 0.0f;

    for (int t0 = 0; t0 < 96; t0 += 16) {
        #pragma unroll
        for (int tt = 0; tt < 16; ++tt) {
            im = im * ib + drive[(t0 + tt) * B + b];
            float isp = (im > it) ? 1.0f : 0.0f;
            im *= (1.0f - isp);
            cbuf[tt][b] = isp * w;
        }
        __syncthreads();
        {
            float s = 0.0f;
            #pragma unroll
            for (int k = 0; k < 16; ++k) s += cbuf[wave][lane + 64 * k];
            #pragma unroll
            for (int off = 32; off; off >>= 1) s += __shfl_xor(s, off);
            if (lane == 0) S[t0 + wave] = s + sc[0];
        }
        __syncthreads();
    }
    {
        #pragma unroll
        for (int tt = 0; tt < 4; ++tt) {
            im = im * ib + drive[(96 + tt) * B + b];
            float isp = (im > it) ? 1.0f : 0.0f;
            im *= (1.0f - isp);
            cbuf[tt][b] = isp * w;
        }
        __syncthreads();
        if (wave < 4) {
            float s = 0.0f;
            #pragma unroll
            for (int k = 0; k < 16; ++k) s += cbuf[wave][lane + 64 * k];
            #pragma unroll
            for (int off = 32; off; off >>= 1) s += __shfl_xor(s, off);
            if (lane == 0) S[96 + wave] = s + sc[0];
        }
        __syncthreads();
    }

    if (b == 0) {
        float hb = hbeta[0], ht = hthr[0];
        float hm = 0.0f, wsum = 0.0f, tasum = 0.0f;
        for (int t = 0; t < T; ++t) {
            hm = hm * hb + S[t];
            float hsp = (hm > ht) ? 1.0f : 0.0f;
            hm *= (1.0f - hsp);
            wsum += ta_l[t] * hsp;
            tasum += ta_l[t];
        }
        sc[1] = wsum; sc[2] = tasum;
    }
    __syncthreads();
    if (b < OUT) out[b] = sc[1] * rowsum[b] + sc[2] * fc2_b[b];
}

extern "C" void kernel_launch(void* const* d_in, const int* in_sizes, int n_in,
                              void* d_out, int out_size, void* d_ws, size_t ws_size,
                              hipStream_t stream) {
    const float* x      = (const float*)d_in[0];
    const float* cd     = (const float*)d_in[1];
    const float* fc1_w  = (const float*)d_in[2];
    const float* fc1_b  = (const float*)d_in[3];
    const float* fc2_w  = (const float*)d_in[4];
    const float* fc2_b  = (const float*)d_in[5];
    const float* ta     = (const float*)d_in[6];
    const float* lor    = (const float*)d_in[7];
    const float* ibeta  = (const float*)d_in[8];
    const float* hbeta  = (const float*)d_in[9];
    const float* ithr   = (const float*)d_in[10];
    const float* hthr   = (const float*)d_in[11];
    float* out = (float*)d_out;

    float* wsf     = (float*)d_ws;
    float* partial = wsf;
    float* rowsum  = wsf + 16384;
    float* drive   = wsf + 16896;

    k_main<<<NDRV + NW1D + NRSUM, 256, 0, stream>>>(x, cd, fc1_w, fc2_w, lor,
                                                    drive, partial, rowsum);
    k_scan<<<1, 1024, 0, stream>>>(drive, partial, cd, fc1_b, fc2_b, ta, lor,
                                   ibeta, hbeta, ithr, hthr, rowsum, out);
}

// Round 10
// 80.923 us; speedup vs baseline: 1.0904x; 1.0904x over previous
//
#include <hip/hip_runtime.h>
#include <math.h>

#define B   1024
#define IN  1024
#define HID 1024
#define OUT 512
#define T   100

// grid split for k_main
#define NDRV (B * T / 4)        // 25600 blocks, one wave per (b,t) row
#define NW1D 64                 // w1d partial blocks
#define NRSUM 128               // fc2 rowsum blocks

typedef float v4f __attribute__((ext_vector_type(4)));

// ---------------------------------------------------------------------------
// Best-known structure (R4/R6, 80.4 us): in-order one-row-per-wave drive with
// nontemporal reads, aux blocks trailing, separate 1-block scan kernel.
// Rationale (measured):
//  - per-block fences / fan-in: 40x regression (R5)
//  - L3-resident split: +16 us (R6->R7 exp)
//  - persistent grid-stride: +7.5 us (R7->R8: frontier scatter)
//  - 4 rows/wave ILP: +7.8 us (R8->R9: VGPR pressure -> occupancy loss)
// ws layout (floats):
//   [0, 16384)            w1d partials (16 h-chunks x 1024 b)
//   [16384, 16896)        rowsum_fc2[o]
//   [16896, 16896+T*B)    drive[t*B+b]
// ---------------------------------------------------------------------------

__device__ __forceinline__ float delay_of(const float* lor, float cdv) {
    float v = fminf(fmaxf(lor[0], 0.0f), 0.999f);
    float g = 1.0f / sqrtf(1.0f - v * v);
    return expf(-g * fabsf(cdv) * v);
}

// blocks [0, NDRV): drive — one wave per (b,t) row, nontemporal x reads
// blocks [NDRV, NDRV+NW1D): w1d partials (hc = q>>2 h-chunk of 64, bb = q&3)
// blocks [NDRV+NW1D, NDRV+NW1D+NRSUM): fc2 rowsums (one wave per output row)
__global__ __launch_bounds__(256) void k_main(const float* __restrict__ x,
                                              const float* __restrict__ cd,
                                              const float* __restrict__ fc1_w,
                                              const float* __restrict__ fc2_w,
                                              const float* __restrict__ lor,
                                              float* __restrict__ drive,
                                              float* __restrict__ partial,
                                              float* __restrict__ rowsum) {
    int blk = blockIdx.x;
    if (blk < NDRV) {
        __shared__ float dly[IN];
        #pragma unroll
        for (int k = 0; k < 4; ++k) {
            int i = k * 256 + threadIdx.x;
            dly[i] = delay_of(lor, cd[i]);
        }
        __syncthreads();
        int gwave = (int)(((size_t)blk * 256 + threadIdx.x) >> 6);
        int lane = threadIdx.x & 63;
        const v4f* xr = (const v4f*)(x + (size_t)gwave * IN);
        const v4f* dl = (const v4f*)dly;
        float acc = 0.0f;
        #pragma unroll
        for (int k = 0; k < 4; ++k) {
            int idx = k * 64 + lane;                       // 16B/lane, coalesced
            v4f xv = __builtin_nontemporal_load(xr + idx); // nt: bypass cache alloc
            v4f dv = dl[idx];
            acc += xv.x * dv.x + xv.y * dv.y + xv.z * dv.z + xv.w * dv.w;
        }
        #pragma unroll
        for (int off = 32; off; off >>= 1) acc += __shfl_xor(acc, off);
        if (lane == 0) {
            int b = gwave / T;
            int t = gwave - b * T;
            drive[t * B + b] = acc;
        }
    } else if (blk < NDRV + NW1D) {
        __shared__ float dly[64];
        int q = blk - NDRV;
        int hc = q >> 2, bb = q & 3;
        int h0 = hc * 64;
        if (threadIdx.x < 64)
            dly[threadIdx.x] = delay_of(lor, cd[h0 + threadIdx.x]);
        __syncthreads();
        int b = bb * 256 + threadIdx.x;
        float acc = 0.0f;
        #pragma unroll 8
        for (int k = 0; k < 64; ++k)
            acc += fc1_w[(size_t)(h0 + k) * IN + b] * dly[k];
        partial[hc * IN + b] = acc;
    } else {
        int gw = ((blk - NDRV - NW1D) * 256 + threadIdx.x) >> 6; // 512 waves -> OUT rows
        int lane = threadIdx.x & 63;
        const float4* r = (const float4*)(fc2_w + (size_t)gw * HID);
        float acc = 0.0f;
        #pragma unroll
        for (int k = 0; k < 4; ++k) {
            float4 v = r[k * 64 + lane];
            acc += v.x + v.y + v.z + v.w;
        }
        #pragma unroll
        for (int off = 32; off; off >>= 1) acc += __shfl_xor(acc, off);
        if (lane == 0) rowsum[gw] = acc;
    }
}

// single block, 1024 threads: c1 + w1d combine + chunked LIF scan + hm scan + output
__global__ __launch_bounds__(1024) void k_scan(const float* __restrict__ drive,
                                               const float* __restrict__ partial,
                                               const float* __restrict__ cd,
                                               const float* __restrict__ fc1_b,
                                               const float* __restrict__ fc2_b,
                                               const float* __restrict__ ta,
                                               const float* __restrict__ lor,
                                               const float* __restrict__ ibeta,
                                               const float* __restrict__ hbeta,
                                               const float* __restrict__ ithr,
                                               const float* __restrict__ hthr,
                                               const float* __restrict__ rowsum,
                                               float* __restrict__ out) {
    __shared__ float cbuf[16][B];   // 64 KB
    __shared__ float red[16];
    __shared__ float S[T];
    __shared__ float ta_l[T];
    __shared__ float sc[4];         // [0]=c1, [1]=wsum, [2]=tasum
    int b = threadIdx.x, wave = b >> 6, lane = b & 63;

    if (b < T) ta_l[b] = ta[b];

    float d = delay_of(lor, cd[b]);
    float c = fc1_b[b] * d;
    #pragma unroll
    for (int off = 32; off; off >>= 1) c += __shfl_xor(c, off);
    if (lane == 0) red[wave] = c;
    __syncthreads();
    if (b == 0) {
        float s = 0.0f;
        #pragma unroll
        for (int k = 0; k < 16; ++k) s += red[k];
        sc[0] = s;
    }

    float w = 0.0f;
    #pragma unroll
    for (int cc = 0; cc < 16; ++cc) w += partial[cc * IN + b];

    float ib = ibeta[0], it = ithr[0];
    float im = 0.0f;

    for (int t0 = 0; t0 < 96; t0 += 16) {
        #pragma unroll
        for (int tt = 0; tt < 16; ++tt) {
            im = im * ib + drive[(t0 + tt) * B + b];
            float isp = (im > it) ? 1.0f : 0.0f;
            im *= (1.0f - isp);
            cbuf[tt][b] = isp * w;
        }
        __syncthreads();
        {
            float s = 0.0f;
            #pragma unroll
            for (int k = 0; k < 16; ++k) s += cbuf[wave][lane + 64 * k];
            #pragma unroll
            for (int off = 32; off; off >>= 1) s += __shfl_xor(s, off);
            if (lane == 0) S[t0 + wave] = s + sc[0];
        }
        __syncthreads();
    }
    {
        #pragma unroll
        for (int tt = 0; tt < 4; ++tt) {
            im = im * ib + drive[(96 + tt) * B + b];
            float isp = (im > it) ? 1.0f : 0.0f;
            im *= (1.0f - isp);
            cbuf[tt][b] = isp * w;
        }
        __syncthreads();
        if (wave < 4) {
            float s = 0.0f;
            #pragma unroll
            for (int k = 0; k < 16; ++k) s += cbuf[wave][lane + 64 * k];
            #pragma unroll
            for (int off = 32; off; off >>= 1) s += __shfl_xor(s, off);
            if (lane == 0) S[96 + wave] = s + sc[0];
        }
        __syncthreads();
    }

    if (b == 0) {
        float hb = hbeta[0], ht = hthr[0];
        float hm = 0.0f, wsum = 0.0f, tasum = 0.0f;
        for (int t = 0; t < T; ++t) {
            hm = hm * hb + S[t];
            float hsp = (hm > ht) ? 1.0f : 0.0f;
            hm *= (1.0f - hsp);
            wsum += ta_l[t] * hsp;
            tasum += ta_l[t];
        }
        sc[1] = wsum; sc[2] = tasum;
    }
    __syncthreads();
    if (b < OUT) out[b] = sc[1] * rowsum[b] + sc[2] * fc2_b[b];
}

extern "C" void kernel_launch(void* const* d_in, const int* in_sizes, int n_in,
                              void* d_out, int out_size, void* d_ws, size_t ws_size,
                              hipStream_t stream) {
    const float* x      = (const float*)d_in[0];
    const float* cd     = (const float*)d_in[1];
    const float* fc1_w  = (const float*)d_in[2];
    const float* fc1_b  = (const float*)d_in[3];
    const float* fc2_w  = (const float*)d_in[4];
    const float* fc2_b  = (const float*)d_in[5];
    const float* ta     = (const float*)d_in[6];
    const float* lor    = (const float*)d_in[7];
    const float* ibeta  = (const float*)d_in[8];
    const float* hbeta  = (const float*)d_in[9];
    const float* ithr   = (const float*)d_in[10];
    const float* hthr   = (const float*)d_in[11];
    float* out = (float*)d_out;

    float* wsf     = (float*)d_ws;
    float* partial = wsf;
    float* rowsum  = wsf + 16384;
    float* drive   = wsf + 16896;

    k_main<<<NDRV + NW1D + NRSUM, 256, 0, stream>>>(x, cd, fc1_w, fc2_w, lor,
                                                    drive, partial, rowsum);
    k_scan<<<1, 1024, 0, stream>>>(drive, partial, cd, fc1_b, fc2_b, ta, lor,
                                   ibeta, hbeta, ithr, hthr, rowsum, out);
}